// Round 4
// baseline (772.404 us; speedup 1.0000x reference)
//
#include <hip/hip_runtime.h>
#include <hip/hip_bf16.h>
#include <math.h>

// ---------------- Problem dims ----------------
#define B       256
#define C1_IH   250
#define P1_H    123
#define P2_H    61
#define FC1_K   55815
#define FC1_N   120
#define FC2_N   84

// fc1 MFMA GEMM config
#define KP        57344            // K padded to 128*448
#define FC1_SPLIT 128
#define FC1_KC    (KP / FC1_SPLIT) // 448

typedef __attribute__((ext_vector_type(8))) short bf16x8;
typedef __attribute__((ext_vector_type(4))) float f32x4;

static __device__ __forceinline__ unsigned short bf16_bits(float f) {
    __hip_bfloat16 h = __float2bfloat16(f);
    return *(unsigned short*)&h;
}

// ================= conv1 (5x5 s2 p1) + ReLU + pool(2,1) -> bf16 pool1 =====
// Block 256 = 16 cg (x4 cols) x 16 rp (x2 rows): conv tile 64x32.
// Grid (2 x-tiles @ conv-col 0/62, 4 y-tiles @ conv-row 31*yt, 256 batch).
__global__ __launch_bounds__(256) void conv1_pool1_kernel(
    const float* __restrict__ x, const float* __restrict__ w1,
    const float* __restrict__ b1, unsigned short* __restrict__ pool1) {
    __shared__ __align__(16) float region[12672]; // in_t 67x132 | out_t 6x32x66
    __shared__ float wlds[600];                   // [tap 75][oc pad 8]
    float* in_t  = region;
    float* out_t = region;

    const int tid = threadIdx.x;
    const int CB = 62 * blockIdx.x;
    const int RB = 31 * blockIdx.y;
    const int b  = blockIdx.z;
    const int cg = tid & 15, rp = tid >> 4;

    for (int f = tid; f < 600; f += 256) {
        int oc = f & 7, k = f >> 3;
        wlds[f] = (oc < 6) ? w1[oc * 75 + k] : 0.f;
    }

    float acc[2][4][6];
    #pragma unroll
    for (int rr = 0; rr < 2; ++rr)
        #pragma unroll
        for (int j = 0; j < 4; ++j)
            #pragma unroll
            for (int o = 0; o < 6; ++o) acc[rr][j][o] = b1[o];

    const int iyb = 2 * RB - 1, ixb = 2 * CB - 1;
    for (int c = 0; c < 3; ++c) {
        __syncthreads();
        const float* xp = x + (size_t)(b * 3 + c) * (250 * 250);
        #pragma unroll
        for (int i = 0; i < 35; ++i) {
            int f = tid + 256 * i;
            if (f < 8844) {
                int row = f / 132, col = f - row * 132;
                int iy = iyb + row, ix = ixb + col;
                float v = 0.f;
                if ((unsigned)iy < 250u && (unsigned)ix < 250u)
                    v = xp[iy * 250 + ix];
                in_t[f] = v;
            }
        }
        __syncthreads();
        const float* wc = &wlds[c * 200];
        #pragma unroll
        for (int ky = 0; ky < 5; ++ky) {
            const float* p0 = &in_t[(4 * rp + ky) * 132 + 8 * cg];
            const float* p1 = p0 + 264;
            float r0[12], r1[12];
            #pragma unroll
            for (int q = 0; q < 3; ++q) {
                float4 v0 = *(const float4*)(p0 + 4 * q);
                float4 v1 = *(const float4*)(p1 + 4 * q);
                r0[4*q] = v0.x; r0[4*q+1] = v0.y; r0[4*q+2] = v0.z; r0[4*q+3] = v0.w;
                r1[4*q] = v1.x; r1[4*q+1] = v1.y; r1[4*q+2] = v1.z; r1[4*q+3] = v1.w;
            }
            #pragma unroll
            for (int kx = 0; kx < 5; ++kx) {
                const float4 wa = *(const float4*)&wc[(ky * 5 + kx) * 8];
                const float2 wb = *(const float2*)&wc[(ky * 5 + kx) * 8 + 4];
                const float wv[6] = {wa.x, wa.y, wa.z, wa.w, wb.x, wb.y};
                #pragma unroll
                for (int j = 0; j < 4; ++j) {
                    const float x0 = r0[2 * j + kx], x1 = r1[2 * j + kx];
                    #pragma unroll
                    for (int o = 0; o < 6; ++o) {
                        acc[0][j][o] += x0 * wv[o];
                        acc[1][j][o] += x1 * wv[o];
                    }
                }
            }
        }
    }
    __syncthreads();
    // write conv+ReLU tile (fp32) rows 2rp,2rp+1 cols 4cg..4cg+3
    #pragma unroll
    for (int o = 0; o < 6; ++o)
        #pragma unroll
        for (int rr = 0; rr < 2; ++rr) {
            float* dst = &out_t[(o * 32 + 2 * rp + rr) * 66 + 4 * cg];
            float2 lo = {fmaxf(acc[rr][0][o], 0.f), fmaxf(acc[rr][1][o], 0.f)};
            float2 hi = {fmaxf(acc[rr][2][o], 0.f), fmaxf(acc[rr][3][o], 0.f)};
            *(float2*)dst = lo;
            *(float2*)(dst + 2) = hi;
        }
    __syncthreads();
    // pool 2x2 s1: items = 6 oc x 31 pyl x 16 col-groups
    for (int it = tid; it < 6 * 31 * 16; it += 256) {
        int g = it & 15, rem = it >> 4;
        int pyl = rem % 31, oc = rem / 31;
        int py = RB + pyl;
        if (py >= 123) continue;
        const float* q0 = &out_t[(oc * 32 + pyl) * 66 + 4 * g];
        const float* q1 = q0 + 66;
        float t0[6], t1[6];
        #pragma unroll
        for (int q = 0; q < 3; ++q) {
            float2 a = *(const float2*)(q0 + 2 * q);
            float2 bq = *(const float2*)(q1 + 2 * q);
            t0[2*q] = a.x; t0[2*q+1] = a.y;
            t1[2*q] = bq.x; t1[2*q+1] = bq.y;
        }
        #pragma unroll
        for (int j = 0; j < 4; ++j) {
            int pxl = 4 * g + j;
            int px = CB + pxl;
            if (pxl < 62 && px < 123) {
                float m = fmaxf(fmaxf(t0[j], t0[j+1]), fmaxf(t1[j], t1[j+1]));
                pool1[((size_t)(b * 6 + oc) * 123 + py) * 123 + px] = bf16_bits(m);
            }
        }
    }
}

// ================= conv2 (3x3 s2 p1) + ReLU + pool(2,1) -> bf16 A =========
// Block 256 = 16 cg (x4 cols) x 16 rp (x1 row): conv tile 64x16.
// Grid (1, 5 y-tiles @ pool-row 15*yt, 256).
__global__ __launch_bounds__(256) void conv2_pool2_kernel(
    const unsigned short* __restrict__ pool1, const float* __restrict__ w2,
    const float* __restrict__ b2, __hip_bfloat16* __restrict__ A) {
    __shared__ __align__(16) float region[8160]; // in_t 33x132 f32 | out_t 15x16x68 bf16
    __shared__ float wlds[864];                  // [tap 54][oc pad 16]
    float* in_t = region;
    unsigned short* out_t = (unsigned short*)region;

    const int tid = threadIdx.x;
    const int RB = 15 * blockIdx.y;
    const int b  = blockIdx.z;
    const int cg = tid & 15, rp = tid >> 4;

    for (int f = tid; f < 864; f += 256) {
        int oc = f & 15, k = f >> 4;
        wlds[f] = (oc < 15) ? w2[oc * 54 + k] : 0.f;
    }

    float acc[4][15];
    #pragma unroll
    for (int j = 0; j < 4; ++j)
        #pragma unroll
        for (int o = 0; o < 15; ++o) acc[j][o] = b2[o];

    const int iyb = 2 * RB - 1;
    for (int c = 0; c < 6; ++c) {
        __syncthreads();
        const unsigned short* pp = pool1 + (size_t)(b * 6 + c) * (123 * 123);
        #pragma unroll
        for (int i = 0; i < 18; ++i) {
            int f = tid + 256 * i;
            if (f < 4356) {
                int row = f / 132, col = f - row * 132;
                int iy = iyb + row, ix = col - 1;
                float v = 0.f;
                if ((unsigned)iy < 123u && (unsigned)ix < 123u) {
                    unsigned int uu = pp[iy * 123 + ix];
                    v = __uint_as_float(uu << 16);
                }
                in_t[f] = v;
            }
        }
        __syncthreads();
        #pragma unroll
        for (int ky = 0; ky < 3; ++ky) {
            const float* p0 = &in_t[(2 * rp + ky) * 132 + 8 * cg];
            float r[12];
            #pragma unroll
            for (int q = 0; q < 3; ++q) {
                float4 v = *(const float4*)(p0 + 4 * q);
                r[4*q] = v.x; r[4*q+1] = v.y; r[4*q+2] = v.z; r[4*q+3] = v.w;
            }
            #pragma unroll
            for (int kx = 0; kx < 3; ++kx) {
                const float* wp = &wlds[(c * 9 + ky * 3 + kx) * 16];
                const float4 w0 = *(const float4*)wp;
                const float4 w1v = *(const float4*)(wp + 4);
                const float4 w2v = *(const float4*)(wp + 8);
                const float4 w3v = *(const float4*)(wp + 12);
                const float wv[15] = {w0.x, w0.y, w0.z, w0.w,
                                      w1v.x, w1v.y, w1v.z, w1v.w,
                                      w2v.x, w2v.y, w2v.z, w2v.w,
                                      w3v.x, w3v.y, w3v.z};
                #pragma unroll
                for (int j = 0; j < 4; ++j) {
                    const float xv = r[2 * j + kx];
                    #pragma unroll
                    for (int o = 0; o < 15; ++o) acc[j][o] += xv * wv[o];
                }
            }
        }
    }
    __syncthreads();
    // write conv+ReLU tile as bf16, row rp, cols 4cg..4cg+3
    #pragma unroll
    for (int o = 0; o < 15; ++o) {
        unsigned short h0 = bf16_bits(fmaxf(acc[0][o], 0.f));
        unsigned short h1 = bf16_bits(fmaxf(acc[1][o], 0.f));
        unsigned short h2 = bf16_bits(fmaxf(acc[2][o], 0.f));
        unsigned short h3 = bf16_bits(fmaxf(acc[3][o], 0.f));
        uint2 pk;
        pk.x = (unsigned int)h0 | ((unsigned int)h1 << 16);
        pk.y = (unsigned int)h2 | ((unsigned int)h3 << 16);
        *(uint2*)&out_t[(o * 16 + rp) * 68 + 4 * cg] = pk;
    }
    __syncthreads();
    // pool: items = 15 oc x 15 pyl x 16 groups; integer max valid (all >= 0)
    for (int it = tid; it < 3600; it += 256) {
        int g = it & 15, rem = it >> 4;
        int pyl = rem % 15, oc = rem / 15;
        int py = RB + pyl;
        if (py >= 61) continue;
        const unsigned short* q0 = &out_t[(oc * 16 + pyl) * 68 + 4 * g];
        const unsigned short* q1 = q0 + 68;
        unsigned short a[5], bq[5];
        uint2 ua = *(const uint2*)q0;
        uint2 ub = *(const uint2*)q1;
        a[0] = ua.x & 0xffff; a[1] = ua.x >> 16; a[2] = ua.y & 0xffff; a[3] = ua.y >> 16;
        a[4] = q0[4];
        bq[0] = ub.x & 0xffff; bq[1] = ub.x >> 16; bq[2] = ub.y & 0xffff; bq[3] = ub.y >> 16;
        bq[4] = q1[4];
        #pragma unroll
        for (int j = 0; j < 4; ++j) {
            int px = 4 * g + j;
            if (px < 61) {
                unsigned short m0 = a[j] > a[j+1] ? a[j] : a[j+1];
                unsigned short m1 = bq[j] > bq[j+1] ? bq[j] : bq[j+1];
                unsigned short m = m0 > m1 ? m0 : m1;
                ((unsigned short*)A)[(size_t)b * KP + (oc * 61 + py) * 61 + px] = m;
            }
        }
    }
}

// ================= fc1_w fp32 -> bf16 (into zeroed, K-padded buffer) ======
__global__ __launch_bounds__(256) void wconv_kernel(
    const float* __restrict__ w, __hip_bfloat16* __restrict__ wb) {
    int k = blockIdx.x * 256 + threadIdx.x;
    int n = blockIdx.y;
    if (k < FC1_K)
        wb[(size_t)n * KP + k] = __float2bfloat16(w[(size_t)n * FC1_K + k]);
}

// ================= fc1: bf16 MFMA split-K GEMM -> fp32 partials ===========
__global__ __launch_bounds__(256) void fc1_mfma_kernel(
    const __hip_bfloat16* __restrict__ A, const __hip_bfloat16* __restrict__ W,
    float* __restrict__ partial) {
    const int wave = threadIdx.x >> 6, lane = threadIdx.x & 63;
    const int mrow = lane & 15, quad = lane >> 4;
    const int m0 = blockIdx.x * 128 + wave * 32;
    const int k0 = blockIdx.y * FC1_KC;

    f32x4 acc[2][8];
    #pragma unroll
    for (int i = 0; i < 2; ++i)
        #pragma unroll
        for (int j = 0; j < 8; ++j) acc[i][j] = (f32x4){0.f, 0.f, 0.f, 0.f};

    const short* Ap = (const short*)A;
    const short* Wp = (const short*)W;
    for (int ks = 0; ks < FC1_KC; ks += 32) {
        const int kk = k0 + ks + quad * 8;
        const bf16x8 a0 = *(const bf16x8*)(Ap + (size_t)(m0 + mrow) * KP + kk);
        const bf16x8 a1 = *(const bf16x8*)(Ap + (size_t)(m0 + 16 + mrow) * KP + kk);
        #pragma unroll
        for (int nt = 0; nt < 8; ++nt) {
            const bf16x8 bb = *(const bf16x8*)(Wp + (size_t)(nt * 16 + mrow) * KP + kk);
            acc[0][nt] = __builtin_amdgcn_mfma_f32_16x16x32_bf16(a0, bb, acc[0][nt], 0, 0, 0);
            acc[1][nt] = __builtin_amdgcn_mfma_f32_16x16x32_bf16(a1, bb, acc[1][nt], 0, 0, 0);
        }
    }
    float* po = partial + (size_t)blockIdx.y * (256 * 128);
    #pragma unroll
    for (int mt = 0; mt < 2; ++mt)
        #pragma unroll
        for (int nt = 0; nt < 8; ++nt)
            #pragma unroll
            for (int r = 0; r < 4; ++r)
                po[(m0 + mt * 16 + quad * 4 + r) * 128 + nt * 16 + mrow] = acc[mt][nt][r];
}

// ====== tail: split-K reduce + bias/ReLU, fc2, fc3, quantum head, softmax ======
__global__ __launch_bounds__(128) void tail_kernel(
    const float* __restrict__ partial, const float* __restrict__ fc1_b,
    const float* __restrict__ fc2_w, const float* __restrict__ fc2_b,
    const float* __restrict__ fc3_w, const float* __restrict__ fc3_b,
    const float* __restrict__ qw, float* __restrict__ out) {
    __shared__ float h1[FC1_N];
    __shared__ float h2[FC2_N];
    __shared__ float ang[4];
    int b = blockIdx.x;
    int t = threadIdx.x;

    if (t < FC1_N) {
        const float* p = partial + b * 128 + t;
        float sum = 0.f;
        #pragma unroll 4
        for (int s = 0; s < FC1_SPLIT; ++s) sum += p[(size_t)s * (256 * 128)];
        h1[t] = fmaxf(sum + fc1_b[t], 0.f);
    }
    __syncthreads();
    if (t < FC2_N) {
        float acc = fc2_b[t];
        const float* w = fc2_w + t * FC1_N;
        for (int k = 0; k < FC1_N; ++k) acc += h1[k] * w[k];
        h2[t] = fmaxf(acc, 0.f);
    }
    __syncthreads();
    if (t < 4) {
        float acc = fc3_b[t];
        const float* w = fc3_w + t * FC2_N;
        for (int k = 0; k < FC2_N; ++k) acc += h2[k] * w[k];
        ang[t] = acc;
    }
    __syncthreads();
    if (t == 0) {
        float sr[16], si[16];
        #pragma unroll
        for (int i = 0; i < 16; ++i) { sr[i] = 0.f; si[i] = 0.f; }
        sr[0] = 1.f;
        for (int q = 0; q < 4; ++q) {
            float th = ang[q] * 0.5f;
            float c = cosf(th), s = sinf(th);
            int mask = 1 << (3 - q);
            #pragma unroll
            for (int i = 0; i < 16; ++i) {
                if (i & mask) continue;
                int i1 = i | mask;
                float a0r = sr[i], a0i = si[i], a1r = sr[i1], a1i = si[i1];
                sr[i]  = c * a0r + s * a1i;
                si[i]  = c * a0i - s * a1r;
                sr[i1] = c * a1r + s * a0i;
                si[i1] = c * a1i - s * a0r;
            }
        }
        int widx = 0;
        for (int d = 0; d < 2; ++d) {
            for (int q = 0; q < 4; ++q) {
                float th = qw[widx++] * 0.5f;
                float c = cosf(th), s = sinf(th);
                int mask = 1 << (3 - q);
                #pragma unroll
                for (int i = 0; i < 16; ++i) {
                    if (i & mask) continue;
                    int i1 = i | mask;
                    float a0r = sr[i], a0i = si[i], a1r = sr[i1], a1i = si[i1];
                    sr[i]  = c * a0r - s * a1r;
                    si[i]  = c * a0i - s * a1i;
                    sr[i1] = s * a0r + c * a1r;
                    si[i1] = s * a0i + c * a1i;
                }
            }
            for (int q = 0; q < 3; ++q) {
                int m1 = 1 << (3 - q), m2 = 1 << (2 - q);
                #pragma unroll
                for (int i = 0; i < 16; ++i) {
                    if ((i & m1) && (i & m2)) { sr[i] = -sr[i]; si[i] = -si[i]; }
                }
            }
        }
        float l0 = 0.f, l1 = 0.f;
        #pragma unroll
        for (int i = 0; i < 16; ++i) {
            float p = sr[i] * sr[i] + si[i] * si[i];
            l0 += (i & 8) ? -p : p;
            l1 += (i & 4) ? -p : p;
        }
        float m = fmaxf(l0, l1);
        float e0 = expf(l0 - m), e1 = expf(l1 - m);
        float inv = 1.f / (e0 + e1);
        out[b * 2 + 0] = e0 * inv;
        out[b * 2 + 1] = e1 * inv;
    }
}

extern "C" void kernel_launch(void* const* d_in, const int* in_sizes, int n_in,
                              void* d_out, int out_size, void* d_ws, size_t ws_size,
                              hipStream_t stream) {
    const float* x     = (const float*)d_in[0];
    const float* w1    = (const float*)d_in[1];
    const float* b1    = (const float*)d_in[2];
    const float* w2    = (const float*)d_in[3];
    const float* b2    = (const float*)d_in[4];
    const float* fc1_w = (const float*)d_in[5];
    const float* fc1_b = (const float*)d_in[6];
    const float* fc2_w = (const float*)d_in[7];
    const float* fc2_b = (const float*)d_in[8];
    const float* fc3_w = (const float*)d_in[9];
    const float* fc3_b = (const float*)d_in[10];
    const float* qw    = (const float*)d_in[11];
    float* out = (float*)d_out;

    // ws layout:
    //   pool1  bf16 (B,6,123,123)   46,476,288 B
    //   A_bf16 (256, KP)            29,360,128 B
    //   W_bf16 (128, KP)            14,680,064 B
    //   partial fp32 (128,256,128)  16,777,216 B
    char* ws = (char*)d_ws;
    unsigned short* pool1   = (unsigned short*)ws;
    __hip_bfloat16* A_bf16  = (__hip_bfloat16*)(ws + 46476288);
    __hip_bfloat16* W_bf16  = (__hip_bfloat16*)(ws + 46476288 + 29360128);
    float*          partial = (float*)(ws + 46476288 + 29360128 + 14680064);

    hipMemsetAsync(W_bf16, 0, (size_t)128 * KP * 2, stream);
    wconv_kernel<<<dim3((FC1_K + 255) / 256, FC1_N), 256, 0, stream>>>(fc1_w, W_bf16);
    conv1_pool1_kernel<<<dim3(2, 4, B), 256, 0, stream>>>(x, w1, b1, pool1);
    conv2_pool2_kernel<<<dim3(1, 5, B), 256, 0, stream>>>(pool1, w2, b2, A_bf16);
    fc1_mfma_kernel<<<dim3(2, FC1_SPLIT), 256, 0, stream>>>(A_bf16, W_bf16, partial);
    tail_kernel<<<B, 128, 0, stream>>>(partial, fc1_b, fc2_w, fc2_b,
                                       fc3_w, fc3_b, qw, out);
}

// Round 5
// 455.986 us; speedup vs baseline: 1.6939x; 1.6939x over previous
//
#include <hip/hip_runtime.h>
#include <hip/hip_bf16.h>
#include <math.h>

// ---------------- dims ----------------
#define B 256
#define FC1_K   55815
#define FC1_N   120
#define FC2_N   84
#define KP        57344
#define FC1_SPLIT 128
#define FC1_KC    (KP / FC1_SPLIT)

typedef __attribute__((ext_vector_type(8))) short bf16x8;
typedef __attribute__((ext_vector_type(4))) float f32x4;

static __device__ __forceinline__ unsigned short bf16_bits(float f) {
    __hip_bfloat16 h = __float2bfloat16(f);
    return *(unsigned short*)&h;
}

// async global->LDS copy, 4 B per lane; lds base must be wave-uniform
#define ASYNC_CP(g, l) __builtin_amdgcn_global_load_lds( \
    (const __attribute__((address_space(1))) void*)(g),  \
    (__attribute__((address_space(3))) void*)(l), 4, 0, 0)

// ---------------- weight re-layout: [oc][c][ky][kx] -> [c][ky][kx][oc] ----
__global__ void wprep_kernel(const float* __restrict__ w1, const float* __restrict__ w2,
                             float* __restrict__ w1p, float* __restrict__ w2p) {
    int t = threadIdx.x;
    for (int f = t; f < 450; f += 256) {
        int o = f % 6, tap = f / 6;
        int kx = tap % 5, r2 = tap / 5, ky = r2 % 5, c = r2 / 5;
        w1p[f] = w1[(o * 3 + c) * 25 + ky * 5 + kx];
    }
    for (int f = t; f < 810; f += 256) {
        int o = f % 15, tap = f / 15;
        int kx = tap % 3, r2 = tap / 3, ky = r2 % 3, c = r2 / 3;
        w2p[f] = w2[(o * 6 + c) * 9 + ky * 3 + kx];
    }
}

// ======== conv1 (5x5 s2 p1) + ReLU + pool(2,1) -> padded bf16 pool1 ========
// pool1 layout: (B, 6, 123, 128) bf16, col idx = px+1 (left pad), pads = 0.
// Block 256 = 32 colgroups x 8 conv rows. Grid (18 y-bands, 256 batch).
__global__ __launch_bounds__(256) void conv1_pool1_kernel(
    const float* __restrict__ x, const float* __restrict__ w1p,
    const float* __restrict__ b1, unsigned short* __restrict__ pool1,
    const float* __restrict__ zeros) {
    __shared__ __align__(16) float in_t[19 * 256 + 8];
    __shared__ __align__(16) unsigned short out_t[6 * 8 * 132];

    const int tid = threadIdx.x;
    const int wave = tid >> 6, lane = tid & 63;
    const int PB = 7 * blockIdx.x;          // pool row base
    const int b  = blockIdx.y;
    const int cg = tid & 31, rr = tid >> 5; // col group (4 cols), conv row 0..7
    const int iyb = 2 * PB - 1;

    float acc[4][6];
    #pragma unroll
    for (int j = 0; j < 4; ++j)
        #pragma unroll
        for (int o = 0; o < 6; ++o) acc[j][o] = b1[o];

    for (int c = 0; c < 3; ++c) {
        __syncthreads();                       // prev channel compute done
        const float* xp = x + (size_t)(b * 3 + c) * 62500;
        #pragma unroll
        for (int i = 0; i < 19; ++i) {
            int chunk = wave * 19 + i;         // 76 chunks of 64 floats
            int f = chunk * 64 + lane;
            int row = f >> 8, m = f & 255;
            int iy = iyb + row, col = m - 1;
            const float* g = ((unsigned)iy < 250u && (unsigned)col < 250u)
                             ? (xp + iy * 250 + col) : zeros;
            ASYNC_CP(g, &in_t[chunk * 64]);
        }
        __syncthreads();                       // drains vmcnt (async copies)
        const float* wc = w1p + c * 150;       // uniform -> s_load
        #pragma unroll
        for (int ky = 0; ky < 5; ++ky) {
            const float* rp = &in_t[(2 * rr + ky) * 256 + 8 * cg];
            float f[12];
            float4 v0 = *(const float4*)rp;
            float4 v1 = *(const float4*)(rp + 4);
            float4 v2 = *(const float4*)(rp + 8);
            f[0]=v0.x; f[1]=v0.y; f[2]=v0.z; f[3]=v0.w;
            f[4]=v1.x; f[5]=v1.y; f[6]=v1.z; f[7]=v1.w;
            f[8]=v2.x; f[9]=v2.y; f[10]=v2.z; f[11]=v2.w;
            #pragma unroll
            for (int kx = 0; kx < 5; ++kx) {
                const float* wp = wc + (ky * 5 + kx) * 6;  // uniform
                #pragma unroll
                for (int j = 0; j < 4; ++j) {
                    float xv = f[2 * j + kx];
                    #pragma unroll
                    for (int o = 0; o < 6; ++o) acc[j][o] += xv * wp[o];
                }
            }
        }
    }
    // write conv+ReLU tile as bf16
    #pragma unroll
    for (int o = 0; o < 6; ++o) {
        unsigned short h0 = bf16_bits(fmaxf(acc[0][o], 0.f));
        unsigned short h1 = bf16_bits(fmaxf(acc[1][o], 0.f));
        unsigned short h2 = bf16_bits(fmaxf(acc[2][o], 0.f));
        unsigned short h3 = bf16_bits(fmaxf(acc[3][o], 0.f));
        uint2 pk;
        pk.x = (unsigned)h0 | ((unsigned)h1 << 16);
        pk.y = (unsigned)h2 | ((unsigned)h3 << 16);
        *(uint2*)&out_t[(o * 8 + rr) * 132 + 4 * cg] = pk;
    }
    __syncthreads();
    // pool 2x2 s1 (integer max on non-negative bf16 bits), write padded pool1
    for (int it = tid; it < 6 * 7 * 32; it += 256) {
        int g = it & 31, rem = it >> 5;
        int pyl = rem % 7, oc = rem / 7;
        int py = PB + pyl;
        if (py >= 123) continue;
        const unsigned short* q0 = &out_t[(oc * 8 + pyl) * 132 + 4 * g];
        const unsigned short* q1 = q0 + 132;
        uint2 ua = *(const uint2*)q0;
        uint2 ub = *(const uint2*)q1;
        unsigned short va[5] = {(unsigned short)(ua.x & 0xffff), (unsigned short)(ua.x >> 16),
                                (unsigned short)(ua.y & 0xffff), (unsigned short)(ua.y >> 16), q0[4]};
        unsigned short vb[5] = {(unsigned short)(ub.x & 0xffff), (unsigned short)(ub.x >> 16),
                                (unsigned short)(ub.y & 0xffff), (unsigned short)(ub.y >> 16), q1[4]};
        unsigned short* dst = pool1 + ((size_t)(b * 6 + oc) * 123 + py) * 128;
        #pragma unroll
        for (int j = 0; j < 4; ++j) {
            int px = 4 * g + j;
            if (px >= 127) continue;
            unsigned short m = 0;
            if (px <= 122) {
                unsigned short m0 = va[j] > va[j+1] ? va[j] : va[j+1];
                unsigned short m1 = vb[j] > vb[j+1] ? vb[j] : vb[j+1];
                m = m0 > m1 ? m0 : m1;
            }
            dst[1 + px] = m;
        }
        if (g == 0) dst[0] = 0;
    }
}

// ======== conv2 (3x3 s2 p1) + ReLU + pool(2,1) -> bf16 A rows ========
// Block 128 = 16 colgroups x 8 conv rows. Grid (9 y-bands, 256 batch).
__global__ __launch_bounds__(128) void conv2_pool2_kernel(
    const unsigned short* __restrict__ pool1, const float* __restrict__ w2p,
    const float* __restrict__ b2, unsigned short* __restrict__ A,
    const unsigned int* __restrict__ zerosu) {
    __shared__ __align__(16) unsigned int in2[17 * 64 + 4];
    __shared__ __align__(16) unsigned short out2[15 * 8 * 68];

    const int tid = threadIdx.x;
    const int wave = tid >> 6, lane = tid & 63;
    const int PB = 7 * blockIdx.x;
    const int b  = blockIdx.y;
    const int cg = tid & 15, rr = tid >> 4;
    const int iyb = 2 * PB - 1;

    float acc[4][15];
    #pragma unroll
    for (int j = 0; j < 4; ++j)
        #pragma unroll
        for (int o = 0; o < 15; ++o) acc[j][o] = b2[o];

    const unsigned int* p1u = (const unsigned int*)pool1;
    for (int c = 0; c < 6; ++c) {
        __syncthreads();
        const unsigned int* pp = p1u + (size_t)(b * 6 + c) * (123 * 64);
        #pragma unroll
        for (int i = 0; i < 9; ++i) {
            int chunk = wave * 9 + i;          // 17 chunks of 64 u32
            if (chunk < 17) {
                int f = chunk * 64 + lane;
                int row = f >> 6, off = f & 63;
                int iy = iyb + row;
                const unsigned int* g = ((unsigned)iy < 123u)
                                        ? (pp + iy * 64 + off) : zerosu;
                ASYNC_CP(g, &in2[chunk * 64]);
            }
        }
        __syncthreads();
        #pragma unroll
        for (int ky = 0; ky < 3; ++ky) {
            const unsigned int* rp = &in2[(2 * rr + ky) * 64 + 4 * cg];
            uint4 u4 = *(const uint4*)rp;
            unsigned int u5 = rp[4];
            float f[10];
            f[0] = __uint_as_float(u4.x << 16); f[1] = __uint_as_float(u4.x & 0xffff0000u);
            f[2] = __uint_as_float(u4.y << 16); f[3] = __uint_as_float(u4.y & 0xffff0000u);
            f[4] = __uint_as_float(u4.z << 16); f[5] = __uint_as_float(u4.z & 0xffff0000u);
            f[6] = __uint_as_float(u4.w << 16); f[7] = __uint_as_float(u4.w & 0xffff0000u);
            f[8] = __uint_as_float(u5  << 16);  f[9] = __uint_as_float(u5  & 0xffff0000u);
            #pragma unroll
            for (int kx = 0; kx < 3; ++kx) {
                const float* wp = w2p + (c * 9 + ky * 3 + kx) * 15;  // uniform
                #pragma unroll
                for (int j = 0; j < 4; ++j) {
                    float xv = f[2 * j + kx];
                    #pragma unroll
                    for (int o = 0; o < 15; ++o) acc[j][o] += xv * wp[o];
                }
            }
        }
    }
    #pragma unroll
    for (int o = 0; o < 15; ++o) {
        unsigned short h0 = bf16_bits(fmaxf(acc[0][o], 0.f));
        unsigned short h1 = bf16_bits(fmaxf(acc[1][o], 0.f));
        unsigned short h2 = bf16_bits(fmaxf(acc[2][o], 0.f));
        unsigned short h3 = bf16_bits(fmaxf(acc[3][o], 0.f));
        uint2 pk;
        pk.x = (unsigned)h0 | ((unsigned)h1 << 16);
        pk.y = (unsigned)h2 | ((unsigned)h3 << 16);
        *(uint2*)&out2[(o * 8 + rr) * 68 + 4 * cg] = pk;
    }
    __syncthreads();
    for (int it = tid; it < 15 * 7 * 16; it += 128) {
        int g = it & 15, rem = it >> 4;
        int pyl = rem % 7, oc = rem / 7;
        int py = PB + pyl;
        if (py >= 61) continue;
        const unsigned short* q0 = &out2[(oc * 8 + pyl) * 68 + 4 * g];
        const unsigned short* q1 = q0 + 68;
        uint2 ua = *(const uint2*)q0;
        uint2 ub = *(const uint2*)q1;
        unsigned short va[5] = {(unsigned short)(ua.x & 0xffff), (unsigned short)(ua.x >> 16),
                                (unsigned short)(ua.y & 0xffff), (unsigned short)(ua.y >> 16), q0[4]};
        unsigned short vb[5] = {(unsigned short)(ub.x & 0xffff), (unsigned short)(ub.x >> 16),
                                (unsigned short)(ub.y & 0xffff), (unsigned short)(ub.y >> 16), q1[4]};
        #pragma unroll
        for (int j = 0; j < 4; ++j) {
            int px = 4 * g + j;
            if (px < 61) {
                unsigned short m0 = va[j] > va[j+1] ? va[j] : va[j+1];
                unsigned short m1 = vb[j] > vb[j+1] ? vb[j] : vb[j+1];
                unsigned short m = m0 > m1 ? m0 : m1;
                A[(size_t)b * KP + (oc * 61 + py) * 61 + px] = m;
            }
        }
    }
}

// ================= fc1_w fp32 -> bf16 (K-padded, pad pre-zeroed) ==========
__global__ __launch_bounds__(256) void wconv_kernel(
    const float* __restrict__ w, __hip_bfloat16* __restrict__ wb) {
    int k = blockIdx.x * 256 + threadIdx.x;
    int n = blockIdx.y;
    if (k < FC1_K)
        wb[(size_t)n * KP + k] = __float2bfloat16(w[(size_t)n * FC1_K + k]);
}

// ================= fc1: bf16 MFMA split-K GEMM -> fp32 partials ===========
__global__ __launch_bounds__(256) void fc1_mfma_kernel(
    const __hip_bfloat16* __restrict__ A, const __hip_bfloat16* __restrict__ W,
    float* __restrict__ partial) {
    const int wave = threadIdx.x >> 6, lane = threadIdx.x & 63;
    const int mrow = lane & 15, quad = lane >> 4;
    const int m0 = blockIdx.x * 128 + wave * 32;
    const int k0 = blockIdx.y * FC1_KC;

    f32x4 acc[2][8];
    #pragma unroll
    for (int i = 0; i < 2; ++i)
        #pragma unroll
        for (int j = 0; j < 8; ++j) acc[i][j] = (f32x4){0.f, 0.f, 0.f, 0.f};

    const short* Ap = (const short*)A;
    const short* Wp = (const short*)W;
    for (int ks = 0; ks < FC1_KC; ks += 32) {
        const int kk = k0 + ks + quad * 8;
        const bf16x8 a0 = *(const bf16x8*)(Ap + (size_t)(m0 + mrow) * KP + kk);
        const bf16x8 a1 = *(const bf16x8*)(Ap + (size_t)(m0 + 16 + mrow) * KP + kk);
        #pragma unroll
        for (int nt = 0; nt < 8; ++nt) {
            const bf16x8 bb = *(const bf16x8*)(Wp + (size_t)(nt * 16 + mrow) * KP + kk);
            acc[0][nt] = __builtin_amdgcn_mfma_f32_16x16x32_bf16(a0, bb, acc[0][nt], 0, 0, 0);
            acc[1][nt] = __builtin_amdgcn_mfma_f32_16x16x32_bf16(a1, bb, acc[1][nt], 0, 0, 0);
        }
    }
    float* po = partial + (size_t)blockIdx.y * (256 * 128);
    #pragma unroll
    for (int mt = 0; mt < 2; ++mt)
        #pragma unroll
        for (int nt = 0; nt < 8; ++nt)
            #pragma unroll
            for (int r = 0; r < 4; ++r)
                po[(m0 + mt * 16 + quad * 4 + r) * 128 + nt * 16 + mrow] = acc[mt][nt][r];
}

// ====== tail: split-K reduce + bias/ReLU, fc2, fc3, quantum head, softmax ==
__global__ __launch_bounds__(128) void tail_kernel(
    const float* __restrict__ partial, const float* __restrict__ fc1_b,
    const float* __restrict__ fc2_w, const float* __restrict__ fc2_b,
    const float* __restrict__ fc3_w, const float* __restrict__ fc3_b,
    const float* __restrict__ qw, float* __restrict__ out) {
    __shared__ float h1[FC1_N];
    __shared__ float h2[FC2_N];
    __shared__ float ang[4];
    int b = blockIdx.x;
    int t = threadIdx.x;

    if (t < FC1_N) {
        const float* p = partial + b * 128 + t;
        float sum = 0.f;
        #pragma unroll 4
        for (int s = 0; s < FC1_SPLIT; ++s) sum += p[(size_t)s * (256 * 128)];
        h1[t] = fmaxf(sum + fc1_b[t], 0.f);
    }
    __syncthreads();
    if (t < FC2_N) {
        float acc = fc2_b[t];
        const float* w = fc2_w + t * FC1_N;
        for (int k = 0; k < FC1_N; ++k) acc += h1[k] * w[k];
        h2[t] = fmaxf(acc, 0.f);
    }
    __syncthreads();
    if (t < 4) {
        float acc = fc3_b[t];
        const float* w = fc3_w + t * FC2_N;
        for (int k = 0; k < FC2_N; ++k) acc += h2[k] * w[k];
        ang[t] = acc;
    }
    __syncthreads();
    if (t == 0) {
        float sr[16], si[16];
        #pragma unroll
        for (int i = 0; i < 16; ++i) { sr[i] = 0.f; si[i] = 0.f; }
        sr[0] = 1.f;
        for (int q = 0; q < 4; ++q) {
            float th = ang[q] * 0.5f;
            float c = cosf(th), s = sinf(th);
            int mask = 1 << (3 - q);
            #pragma unroll
            for (int i = 0; i < 16; ++i) {
                if (i & mask) continue;
                int i1 = i | mask;
                float a0r = sr[i], a0i = si[i], a1r = sr[i1], a1i = si[i1];
                sr[i]  = c * a0r + s * a1i;
                si[i]  = c * a0i - s * a1r;
                sr[i1] = c * a1r + s * a0i;
                si[i1] = c * a1i - s * a0r;
            }
        }
        int widx = 0;
        for (int d = 0; d < 2; ++d) {
            for (int q = 0; q < 4; ++q) {
                float th = qw[widx++] * 0.5f;
                float c = cosf(th), s = sinf(th);
                int mask = 1 << (3 - q);
                #pragma unroll
                for (int i = 0; i < 16; ++i) {
                    if (i & mask) continue;
                    int i1 = i | mask;
                    float a0r = sr[i], a0i = si[i], a1r = sr[i1], a1i = si[i1];
                    sr[i]  = c * a0r - s * a1r;
                    si[i]  = c * a0i - s * a1i;
                    sr[i1] = s * a0r + c * a1r;
                    si[i1] = s * a0i + c * a1i;
                }
            }
            for (int q = 0; q < 3; ++q) {
                int m1 = 1 << (3 - q), m2 = 1 << (2 - q);
                #pragma unroll
                for (int i = 0; i < 16; ++i) {
                    if ((i & m1) && (i & m2)) { sr[i] = -sr[i]; si[i] = -si[i]; }
                }
            }
        }
        float l0 = 0.f, l1 = 0.f;
        #pragma unroll
        for (int i = 0; i < 16; ++i) {
            float p = sr[i] * sr[i] + si[i] * si[i];
            l0 += (i & 8) ? -p : p;
            l1 += (i & 4) ? -p : p;
        }
        float m = fmaxf(l0, l1);
        float e0 = expf(l0 - m), e1 = expf(l1 - m);
        float inv = 1.f / (e0 + e1);
        out[b * 2 + 0] = e0 * inv;
        out[b * 2 + 1] = e1 * inv;
    }
}

extern "C" void kernel_launch(void* const* d_in, const int* in_sizes, int n_in,
                              void* d_out, int out_size, void* d_ws, size_t ws_size,
                              hipStream_t stream) {
    const float* x     = (const float*)d_in[0];
    const float* w1    = (const float*)d_in[1];
    const float* b1    = (const float*)d_in[2];
    const float* w2    = (const float*)d_in[3];
    const float* b2    = (const float*)d_in[4];
    const float* fc1_w = (const float*)d_in[5];
    const float* fc1_b = (const float*)d_in[6];
    const float* fc2_w = (const float*)d_in[7];
    const float* fc2_b = (const float*)d_in[8];
    const float* fc3_w = (const float*)d_in[9];
    const float* fc3_b = (const float*)d_in[10];
    const float* qw    = (const float*)d_in[11];
    float* out = (float*)d_out;

    // ws layout (all 256-B aligned):
    char* ws = (char*)d_ws;
    const size_t O_POOL1  = 0;                         // (B,6,123,128) bf16 = 48,365,568
    const size_t O_A      = O_POOL1 + 48365568;        // (256,KP) bf16     = 29,360,128
    const size_t O_W      = O_A + 29360128;            // (128,KP) bf16     = 14,680,064
    const size_t O_PART   = O_W + 14680064;            // (128,256,128) f32 = 16,777,216
    const size_t O_W1P    = O_PART + 16777216;         // 450 f32 (pad 2048)
    const size_t O_W2P    = O_W1P + 2048;              // 810 f32 (pad 4096)
    const size_t O_ZERO   = O_W2P + 4096;              // 256 B zeros
    unsigned short* pool1   = (unsigned short*)(ws + O_POOL1);
    __hip_bfloat16* A_bf16  = (__hip_bfloat16*)(ws + O_A);
    __hip_bfloat16* W_bf16  = (__hip_bfloat16*)(ws + O_W);
    float*          partial = (float*)(ws + O_PART);
    float*          w1p     = (float*)(ws + O_W1P);
    float*          w2p     = (float*)(ws + O_W2P);
    float*          zeros   = (float*)(ws + O_ZERO);

    hipMemsetAsync(W_bf16, 0, (size_t)128 * KP * 2, stream);
    hipMemsetAsync(zeros, 0, 256, stream);
    wprep_kernel<<<1, 256, 0, stream>>>(w1, w2, w1p, w2p);
    wconv_kernel<<<dim3((FC1_K + 255) / 256, FC1_N), 256, 0, stream>>>(fc1_w, W_bf16);
    conv1_pool1_kernel<<<dim3(18, B), 256, 0, stream>>>(x, w1p, b1, pool1, zeros);
    conv2_pool2_kernel<<<dim3(9, B), 128, 0, stream>>>(pool1, w2p, b2,
                                                       (unsigned short*)A_bf16,
                                                       (const unsigned int*)zeros);
    fc1_mfma_kernel<<<dim3(2, FC1_SPLIT), 256, 0, stream>>>(A_bf16, W_bf16, partial);
    tail_kernel<<<B, 128, 0, stream>>>(partial, fc1_b, fc2_w, fc2_b,
                                       fc3_w, fc3_b, qw, out);
}